// Round 10
// baseline (5725.072 us; speedup 1.0000x reference)
//
#include <hip/hip_runtime.h>

// ---------------------------------------------------------------------------
// VanillaRNN on MI355X (gfx950)   [R10: LDS-free full-K waves, 6-phase step]
// B=128, S=1024, H=1024, E=512, V=256
//
//  3. rnn_seq: 128 WGs x 256 thr. group g = wg&7 (16 batch rows); 16 WGs per
//     group; each WAVE owns 16 h-columns with FULL K=1024 (W_hh slice =
//     32 x bhalf8 = 128 VGPRs). Per step: poll 16 WG-flags -> 32 A-loads ->
//     32 MFMAs (2 chains) -> +proj, tanh -> 4 bf16 stores -> __syncthreads
//     (vmcnt drain) -> publish flag. No LDS, no reduce, one barrier.
//     Flags: R7-proven relaxed-agent store + relaxed-agent load poll
//     (R9's atomic scheme reverted: atomics execute memory-side => +500MB
//     writes, no latency gain).
// ---------------------------------------------------------------------------

typedef __attribute__((ext_vector_type(8))) short bhalf8;   // 8 bf16 (4 VGPR)
typedef __attribute__((ext_vector_type(4))) float floatx4;  // 4 f32

typedef unsigned short u16;
typedef unsigned int u32;

#define B_  128
#define S_  1024
#define H_  1024
#define E_  512
#define V_  256

// ws layout (bytes)
#define WHH_OFF       (268697600ull)            // 128*1025*1024*2 (h_all)
#define WHO_OFF       (WHH_OFF + 2097152ull)    // 1024*1024*2
#define PROJ_OFF      (WHO_OFF + 524288ull)     // 256*1024*2
#define CNT_OFF       (PROJ_OFF + 1048576ull)   // 256*1024*4
// flags: 8 groups x 16 WGs x 16 ints (64B stride) = 2048 ints (zero 4096)

#define FLAG_STRIDE   16                        // ints (64 B)
#define NFLAGS        4096
#define SPIN_CAP      4096                      // bounded spin: fail-loud

__device__ inline u16 f2bf(float f) {
    u32 u = __builtin_bit_cast(u32, f);
    u32 lsb = (u >> 16) & 1u;
    u += 0x7fffu + lsb;
    return (u16)(u >> 16);
}
__device__ inline float bf2f(u16 h) {
    u32 u = ((u32)h) << 16;
    return __builtin_bit_cast(float, u);
}
__device__ inline bhalf8 ld8(const u16* p) {
    return *(const bhalf8*)p;
}

// ---------------------------------------------------------------------------
// 1. prep
// ---------------------------------------------------------------------------
__global__ __launch_bounds__(256) void prep_kernel(
    const float* __restrict__ W_hh, const float* __restrict__ W_ho,
    const float* __restrict__ hidden,
    u16* __restrict__ Whh_bf, u16* __restrict__ Who_bf,
    u16* __restrict__ h_all, int* __restrict__ cnt)
{
    int i = blockIdx.x * 256 + threadIdx.x;
    if (i < 1048576) {
        Whh_bf[i] = f2bf(W_hh[i]);
    } else if (i < 1048576 + 262144) {
        int j = i - 1048576;
        Who_bf[j] = f2bf(W_ho[j]);
    } else if (i < 1048576 + 262144 + 131072) {
        int j = i - (1048576 + 262144);
        int b = j >> 10, k = j & 1023;
        h_all[(size_t)b * 1025 * 1024 + k] = f2bf(hidden[j]);   // t = 0 row
    } else if (i < 1048576 + 262144 + 131072 + NFLAGS) {
        cnt[i - (1048576 + 262144 + 131072)] = 0;
    }
}

// ---------------------------------------------------------------------------
// 2. proj table: proj[v][h] = b_ih[h] + b_hh[h] + sum_e emb[v][e]*W_ih[h][e]
// ---------------------------------------------------------------------------
__global__ __launch_bounds__(256) void proj_kernel(
    const float* __restrict__ emb, const float* __restrict__ W_ih,
    const float* __restrict__ b_ih, const float* __restrict__ b_hh,
    float* __restrict__ proj)
{
    __shared__ float er[E_];
    int v = blockIdx.x, tid = threadIdx.x;
    er[tid]       = emb[v * E_ + tid];
    er[tid + 256] = emb[v * E_ + 256 + tid];
    __syncthreads();
    const float4* x = (const float4*)er;
    #pragma unroll
    for (int j = 0; j < 4; ++j) {
        int hc = tid + j * 256;
        const float4* w = (const float4*)&W_ih[(size_t)hc * E_];
        float s = 0.f;
        #pragma unroll 8
        for (int e = 0; e < E_ / 4; ++e) {
            float4 ww = w[e]; float4 xx = x[e];
            s += ww.x * xx.x + ww.y * xx.y + ww.z * xx.z + ww.w * xx.w;
        }
        proj[v * H_ + hc] = s + b_ih[hc] + b_hh[hc];
    }
}

// ---------------------------------------------------------------------------
// 3. persistent sequential RNN kernel (LDS-free)
//    128 WGs x 256 thr. group = wg&7, wgslot = wg>>3 (0..15).
//    Wave w owns cols [wgslot*64 + w*16, +16), full K=1024.
// ---------------------------------------------------------------------------
__global__ __launch_bounds__(256, 1) void rnn_seq(
    const int* __restrict__ seq, const float* __restrict__ proj,
    const u16* __restrict__ Whh, u16* __restrict__ h_all,
    int* __restrict__ cnt)
{
    const int wg = blockIdx.x;          // 0..127
    const int g = wg & 7;
    const int wgslot = wg >> 3;         // 0..15 within group
    const int tid = threadIdx.x;
    const int wave = tid >> 6;
    const int lane = tid & 63;
    const int l16 = lane & 15, lq = lane >> 4;
    const int col = wgslot * 64 + wave * 16 + l16;   // this lane's h-column

    // W_hh column slice, full K: 32 k-steps (k = ks*32 + lq*8)
    bhalf8 bfrag[32];
    #pragma unroll
    for (int ks = 0; ks < 32; ++ks)
        bfrag[ks] = ld8(&Whh[(size_t)col * H_ + ks * 32 + lq * 8]);

    int* gflags = cnt + g * 16 * FLAG_STRIDE;
    int* myflag = gflags + wgslot * FLAG_STRIDE;
    int* pollp  = gflags + (lane & 15) * FLAG_STRIDE;

    const int b0 = g * 16;
    // A-frag row (batch row) = b0 + l16
    const size_t aRowBase = ((size_t)(b0 + l16) * 1025) * 1024;
    // store rows (from D layout): batch row = b0 + lq*4 + j
    size_t sRow[4];
    int qBase[4];
    #pragma unroll
    for (int j = 0; j < 4; ++j) {
        int brow = b0 + lq * 4 + j;
        sRow[j] = ((size_t)brow * 1025) * 1024 + col;
        qBase[j] = brow * S_;
    }

    // prologue: proj values for t=0 (per lane: 4 rows x 1 col)
    float pj[4];
    #pragma unroll
    for (int j = 0; j < 4; ++j)
        pj[j] = proj[seq[qBase[j]] * H_ + col];

    for (int t = 0; t < S_; ++t) {
        // --- wait for h_t (t>=1): all 16 WG-flags of this group >= t ---
        if (t > 0) {
            int spins = 0;
            for (;;) {
                int v = (lane < 16)
                    ? __hip_atomic_load(pollp, __ATOMIC_RELAXED, __HIP_MEMORY_SCOPE_AGENT)
                    : 0x7fffffff;
                if (__all(v >= t)) break;
                if (++spins > SPIN_CAP) break;   // safety valve: fail loud
                __builtin_amdgcn_s_sleep(1);
            }
            asm volatile("" ::: "memory");   // no h-load hoist above the wait
        }

        // --- A loads + 32 MFMAs (2 independent chains) ---
        const u16* hp = h_all + aRowBase + (size_t)t * 1024 + lq * 8;
        floatx4 acc0 = {0.f, 0.f, 0.f, 0.f};
        floatx4 acc1 = {0.f, 0.f, 0.f, 0.f};
        #pragma unroll
        for (int ks = 0; ks < 32; ks += 2) {
            bhalf8 a0 = ld8(hp + ks * 32);
            bhalf8 a1 = ld8(hp + ks * 32 + 32);
            acc0 = __builtin_amdgcn_mfma_f32_16x16x32_bf16(a0, bfrag[ks],     acc0, 0, 0, 0);
            acc1 = __builtin_amdgcn_mfma_f32_16x16x32_bf16(a1, bfrag[ks + 1], acc1, 0, 0, 0);
        }

        // --- prefetch next step's proj (hides under epilogue+barrier+poll) ---
        float pj2[4];
        const int tn = (t + 1 < S_) ? t + 1 : t;
        #pragma unroll
        for (int j = 0; j < 4; ++j)
            pj2[j] = proj[seq[qBase[j] + tn] * H_ + col];

        // --- epilogue: z = acc0+acc1+proj, tanh, bf16 store (4 rows) ---
        #pragma unroll
        for (int j = 0; j < 4; ++j) {
            float z = acc0[j] + acc1[j] + pj[j];
            h_all[sRow[j] + (size_t)(t + 1) * 1024] = f2bf(tanhf(z));
        }

        // --- barrier drains all 4 waves' stores (vmcnt 0) to L2, then
        //     publish: relaxed agent store (R7-proven visibility) ---
        __syncthreads();
        if (tid == 0)
            __hip_atomic_store(myflag, t + 1, __ATOMIC_RELAXED, __HIP_MEMORY_SCOPE_AGENT);

        #pragma unroll
        for (int j = 0; j < 4; ++j) pj[j] = pj2[j];
    }
}

// ---------------------------------------------------------------------------
// 4. output GEMM: out[b][s][v] = dot(h_all[b][s+1][:], W_ho[v][:]) + b_ho[v]
// ---------------------------------------------------------------------------
__global__ __launch_bounds__(256) void out_gemm(
    const u16* __restrict__ h_all, const u16* __restrict__ Who,
    const float* __restrict__ b_ho, float* __restrict__ out)
{
    const int wg = blockIdx.x;          // 2048 = 128 b x 16 s-tiles
    const int b = wg >> 4;
    const int st = wg & 15;
    const int sbase = st * 64;
    const int tid = threadIdx.x;
    const int wave = tid >> 6;
    const int lane = tid & 63;
    const int l16 = lane & 15, lq = lane >> 4;
    const int vb = wave * 64;

    floatx4 acc[4][4] = {};             // [s-sub][v-sub]
    size_t arow[4];
    #pragma unroll
    for (int ss = 0; ss < 4; ++ss)
        arow[ss] = ((size_t)b * 1025 + sbase + ss * 16 + l16 + 1) * 1024;

    for (int ks = 0; ks < 32; ++ks) {
        const int k = ks * 32 + lq * 8;
        bhalf8 bb[4];
        #pragma unroll
        for (int vt = 0; vt < 4; ++vt)
            bb[vt] = ld8(&Who[(size_t)(vb + vt * 16 + l16) * H_ + k]);
        #pragma unroll
        for (int ss = 0; ss < 4; ++ss) {
            bhalf8 aa = ld8(&h_all[arow[ss] + k]);
            #pragma unroll
            for (int vt = 0; vt < 4; ++vt)
                acc[ss][vt] = __builtin_amdgcn_mfma_f32_16x16x32_bf16(aa, bb[vt], acc[ss][vt], 0, 0, 0);
        }
    }
    #pragma unroll
    for (int ss = 0; ss < 4; ++ss) {
        #pragma unroll
        for (int vt = 0; vt < 4; ++vt) {
            int v = vb + vt * 16 + l16;
            float bias = b_ho[v];
            #pragma unroll
            for (int j = 0; j < 4; ++j) {
                int s = sbase + ss * 16 + lq * 4 + j;
                out[((size_t)b << 18) + (size_t)s * V_ + v] = acc[ss][vt][j] + bias;
            }
        }
    }
}

// ---------------------------------------------------------------------------
// 5. h_final
// ---------------------------------------------------------------------------
__global__ __launch_bounds__(256) void hfinal(const u16* __restrict__ h_all,
                                              float* __restrict__ out)
{
    int i = blockIdx.x * 256 + threadIdx.x;   // 131072
    int b = i >> 10, k = i & 1023;
    out[33554432 + i] = bf2f(h_all[((size_t)b * 1025 + 1024) * 1024 + k]);
}

// ---------------------------------------------------------------------------
extern "C" void kernel_launch(void* const* d_in, const int* in_sizes, int n_in,
                              void* d_out, int out_size, void* d_ws, size_t ws_size,
                              hipStream_t stream) {
    const int*   seq    = (const int*)  d_in[0];
    const float* hidden = (const float*)d_in[1];
    const float* emb    = (const float*)d_in[2];
    const float* W_ih   = (const float*)d_in[3];
    const float* b_ih   = (const float*)d_in[4];
    const float* W_hh   = (const float*)d_in[5];
    const float* b_hh   = (const float*)d_in[6];
    const float* W_ho   = (const float*)d_in[7];
    const float* b_ho   = (const float*)d_in[8];
    float* out = (float*)d_out;

    char* ws = (char*)d_ws;
    u16*   h_all  = (u16*)ws;
    u16*   Whh_bf = (u16*)(ws + WHH_OFF);
    u16*   Who_bf = (u16*)(ws + WHO_OFF);
    float* proj   = (float*)(ws + PROJ_OFF);
    int*   cnt    = (int*)(ws + CNT_OFF);

    prep_kernel<<<5648, 256, 0, stream>>>(W_hh, W_ho, hidden, Whh_bf, Who_bf, h_all, cnt);
    proj_kernel<<<256, 256, 0, stream>>>(emb, W_ih, b_ih, b_hh, proj);
    rnn_seq<<<128, 256, 0, stream>>>(seq, proj, Whh_bf, h_all, cnt);
    out_gemm<<<2048, 256, 0, stream>>>(h_all, Who_bf, b_ho, out);
    hfinal<<<512, 256, 0, stream>>>(h_all, out);
}

// Round 11
// 3494.807 us; speedup vs baseline: 1.6382x; 1.6382x over previous
//
#include <hip/hip_runtime.h>

// ---------------------------------------------------------------------------
// VanillaRNN on MI355X (gfx950)   [R11 = R7 skeleton, flags moved to XCD-L2
//                                  via sc0 store + sc0-nt poll (no L1 alloc)]
// B=128, S=1024, H=1024, E=512, V=256
//
//  1. prep:   bf16-convert W_hh, W_ho; h_all[:,0,:] = hidden; zero flags
//  2. proj:   proj[v][h] = b_ih[h] + b_hh[h] + dot(emb[v,:], W_ih[h,:])  (fp32)
//  3. rnn_seq: persistent kernel, 8 groups x 32 WGs (group = wg&7 -> XCD),
//             group owns 16 batch rows; W_hh slice in VGPRs; 4-wave K-split;
//             LDS reduce; tanh; bf16 store.
//             Sync/step: __syncthreads (vmcnt0: h stores acked by XCD L2) ->
//             leader sc0 STORE (write-through, lands in XCD L2) -> waves poll
//             their 8 producer flags with sc0+nt LOADS (nt = no L1 allocate;
//             flag lines never enter any L1 because every reader is nt and
//             stores are write-through no-allocate => polls are L2-served,
//             ~250cy, and can never see a stale L1 copy — this is the
//             mechanistic fix for R8's failure). No agent-scope ops in the
//             loop: no buffer_wbl2 / buffer_inv / fabric RTT.
//  4. out_gemm: out[b,s,v] = dot(h_all[b,s+1,:], W_ho[v,:]) + b_ho[v]  (MFMA)
//  5. hfinal: d_out tail = fp32(h_all[:,S,:])
// ---------------------------------------------------------------------------

typedef __attribute__((ext_vector_type(8))) short bhalf8;   // 8 bf16 (4 VGPR)
typedef __attribute__((ext_vector_type(4))) float floatx4;  // 4 f32

typedef unsigned short u16;
typedef unsigned int u32;

#define B_  128
#define S_  1024
#define H_  1024
#define E_  512
#define V_  256

// ws layout (bytes)
#define WHH_OFF       (268697600ull)            // 128*1025*1024*2 (h_all)
#define WHO_OFF       (WHH_OFF + 2097152ull)    // 1024*1024*2
#define PROJ_OFF      (WHO_OFF + 524288ull)     // 256*1024*2
#define CNT_OFF       (PROJ_OFF + 1048576ull)   // 256*1024*4
// flags: 8 groups x 32 slots x 16 ints (64B stride) = 4096 ints = 16 KB

#define FLAG_STRIDE   16                        // ints (64 B)
#define NFLAGS        4096
#define SPIN_CAP      16384                     // bounded spin: fail-loud

__device__ inline u16 f2bf(float f) {
    u32 u = __builtin_bit_cast(u32, f);
    u32 lsb = (u >> 16) & 1u;
    u += 0x7fffu + lsb;
    return (u16)(u >> 16);
}
__device__ inline float bf2f(u16 h) {
    u32 u = ((u32)h) << 16;
    return __builtin_bit_cast(float, u);
}
__device__ inline bhalf8 ld8(const u16* p) {
    return *(const bhalf8*)p;
}

// Flag transport at the XCD's shared L2:
//  - store: sc0, write-through (L1 is write-through/no-allocate) -> dirty in L2
//  - load:  sc0 + nt: no L1 allocation; since flags are ONLY ever read via nt
//    and written via write-through stores, the line never exists in any L1,
//    so every poll is served by the L2 (fresh, ~250cy).
__device__ inline int poll_flag_l2(const int* p) {
    int v;
    asm volatile("global_load_dword %0, %1, off sc0 nt\n\ts_waitcnt vmcnt(0)"
                 : "=v"(v) : "v"(p) : "memory");
    return v;
}
__device__ inline void publish_flag_l2(int* p, int v) {
    asm volatile("global_store_dword %0, %1, off sc0"
                 :: "v"(p), "v"(v) : "memory");
}

// ---------------------------------------------------------------------------
// 1. prep
// ---------------------------------------------------------------------------
__global__ __launch_bounds__(256) void prep_kernel(
    const float* __restrict__ W_hh, const float* __restrict__ W_ho,
    const float* __restrict__ hidden,
    u16* __restrict__ Whh_bf, u16* __restrict__ Who_bf,
    u16* __restrict__ h_all, int* __restrict__ cnt)
{
    int i = blockIdx.x * 256 + threadIdx.x;
    if (i < 1048576) {
        Whh_bf[i] = f2bf(W_hh[i]);
    } else if (i < 1048576 + 262144) {
        int j = i - 1048576;
        Who_bf[j] = f2bf(W_ho[j]);
    } else if (i < 1048576 + 262144 + 131072) {
        int j = i - (1048576 + 262144);
        int b = j >> 10, k = j & 1023;
        h_all[(size_t)b * 1025 * 1024 + k] = f2bf(hidden[j]);   // t = 0 row
    } else if (i < 1048576 + 262144 + 131072 + NFLAGS) {
        cnt[i - (1048576 + 262144 + 131072)] = 0;
    }
}

// ---------------------------------------------------------------------------
// 2. proj table: proj[v][h] = b_ih[h] + b_hh[h] + sum_e emb[v][e]*W_ih[h][e]
// ---------------------------------------------------------------------------
__global__ __launch_bounds__(256) void proj_kernel(
    const float* __restrict__ emb, const float* __restrict__ W_ih,
    const float* __restrict__ b_ih, const float* __restrict__ b_hh,
    float* __restrict__ proj)
{
    __shared__ float er[E_];
    int v = blockIdx.x, tid = threadIdx.x;
    er[tid]       = emb[v * E_ + tid];
    er[tid + 256] = emb[v * E_ + 256 + tid];
    __syncthreads();
    const float4* x = (const float4*)er;
    #pragma unroll
    for (int j = 0; j < 4; ++j) {
        int hc = tid + j * 256;
        const float4* w = (const float4*)&W_ih[(size_t)hc * E_];
        float s = 0.f;
        #pragma unroll 8
        for (int e = 0; e < E_ / 4; ++e) {
            float4 ww = w[e]; float4 xx = x[e];
            s += ww.x * xx.x + ww.y * xx.y + ww.z * xx.z + ww.w * xx.w;
        }
        proj[v * H_ + hc] = s + b_ih[hc] + b_hh[hc];
    }
}

// ---------------------------------------------------------------------------
// 3. persistent sequential RNN kernel  (R7 structure, L2-local flags)
//    grid = 256 WGs x 256 threads. group g = wg&7 (XCD-aligned), 32 WGs/group,
//    group owns batch rows [g*16, g*16+16). WG owns 32 h-columns. 4 waves
//    split K=1024 into 256-slices; LDS reduce; tanh; bf16 store.
// ---------------------------------------------------------------------------
__global__ __launch_bounds__(256) void rnn_seq(
    const int* __restrict__ seq, const float* __restrict__ proj,
    const u16* __restrict__ Whh, u16* __restrict__ h_all,
    int* __restrict__ cnt)
{
    const int wg = blockIdx.x;
    const int g = wg & 7;
    const int wslot = wg >> 3;          // 0..31 within group
    const int colbase = wslot * 32;
    const int tid = threadIdx.x;
    const int wave = tid >> 6;
    const int lane = tid & 63;
    const int l16 = lane & 15, lq = lane >> 4;
    const int kb = wave * 256;          // wave's K-slice base

    // W_hh slice resident in registers: 2 col-tiles x 8 k-steps
    bhalf8 bfrag[2][8];
    #pragma unroll
    for (int tt = 0; tt < 2; ++tt) {
        #pragma unroll
        for (int ks = 0; ks < 8; ++ks) {
            bfrag[tt][ks] = ld8(&Whh[(size_t)(colbase + tt * 16 + l16) * H_
                                     + kb + ks * 32 + lq * 8]);
        }
    }

    __shared__ float red[4][2][16][17];   // [wave][tile][row][col+pad]

    int* gflags = cnt + g * 32 * FLAG_STRIDE;
    int* myflag = gflags + wslot * FLAG_STRIDE;
    // wave w consumes h cols [w*256, w*256+256) = wslots [w*8, w*8+8)
    int* pollp  = gflags + (wave * 8 + (lane & 7)) * FLAG_STRIDE;

    const int b0 = g * 16;
    const size_t aRowBase = ((size_t)(b0 + l16) * 1025) * 1024;  // per-lane h row

    // reduce-phase fixed indices
    const int rr = tid & 15;            // batch row within group
    const int cp = tid >> 4;            // 0..15 -> col pair
    const int c0 = 2 * cp, c1 = c0 + 1;
    const size_t hOutBase = ((size_t)(b0 + rr) * 1025) * 1024 + colbase + c0;
    const int seqBase = (b0 + rr) * S_;

    for (int t = 0; t < S_; ++t) {
        // early load (independent of h): token
        int tok = seq[seqBase + t];

        // --- MFMA: z_partial[16 x 32] over this wave's K-slice ---
        const u16* hp = h_all + aRowBase + (size_t)t * 1024 + kb + lq * 8;
        floatx4 acc0 = {0.f, 0.f, 0.f, 0.f};
        floatx4 acc1 = {0.f, 0.f, 0.f, 0.f};
        #pragma unroll
        for (int ks = 0; ks < 8; ++ks) {
            bhalf8 a = ld8(hp + ks * 32);
            acc0 = __builtin_amdgcn_mfma_f32_16x16x32_bf16(a, bfrag[0][ks], acc0, 0, 0, 0);
            acc1 = __builtin_amdgcn_mfma_f32_16x16x32_bf16(a, bfrag[1][ks], acc1, 0, 0, 0);
        }
        float2 pj = *(const float2*)&proj[tok * H_ + colbase + c0];

        #pragma unroll
        for (int j = 0; j < 4; ++j) {    // D layout: row=(lq*4+j), col=l16
            red[wave][0][lq * 4 + j][l16] = acc0[j];
            red[wave][1][lq * 4 + j][l16] = acc1[j];
        }
        __syncthreads();

        // --- reduce 4 waves + x_proj + tanh + bf16 store (2 cols/thread) ---
        float z0 = red[0][c0 >> 4][rr][c0 & 15] + red[1][c0 >> 4][rr][c0 & 15]
                 + red[2][c0 >> 4][rr][c0 & 15] + red[3][c0 >> 4][rr][c0 & 15] + pj.x;
        float z1 = red[0][c1 >> 4][rr][c1 & 15] + red[1][c1 >> 4][rr][c1 & 15]
                 + red[2][c1 >> 4][rr][c1 & 15] + red[3][c1 >> 4][rr][c1 & 15] + pj.y;
        u32 pack = (u32)f2bf(tanhf(z0)) | ((u32)f2bf(tanhf(z1)) << 16);
        *(u32*)&h_all[hOutBase + (size_t)(t + 1) * 1024] = pack;

        // --- sync: drains all waves' h stores to the XCD L2 (vmcnt 0 before
        //     barrier) and protects `red` for next iteration ---
        __syncthreads();

        // --- publish: sc0 write-through store -> dirty in this XCD's L2 ---
        if (tid == 0)
            publish_flag_l2(myflag, t + 1);

        // --- per-wave wait on its 8 producer WGs via sc0+nt L2 reads
        //     (skip after last step). Bounded spin: fail-loud, never hang. ---
        if (t < S_ - 1) {
            const int target = t + 1;
            int spins = 0;
            for (;;) {
                int v = (lane < 8) ? poll_flag_l2(pollp) : 0x7fffffff;
                if (__all(v >= target)) break;
                if (++spins > SPIN_CAP) break;   // safety valve
            }
            asm volatile("" ::: "memory");   // no h-load hoist above the wait
        }
    }
}

// ---------------------------------------------------------------------------
// 4. output GEMM: out[b][s][v] = dot(h_all[b][s+1][:], W_ho[v][:]) + b_ho[v]
// ---------------------------------------------------------------------------
__global__ __launch_bounds__(256) void out_gemm(
    const u16* __restrict__ h_all, const u16* __restrict__ Who,
    const float* __restrict__ b_ho, float* __restrict__ out)
{
    const int wg = blockIdx.x;          // 2048 = 128 b x 16 s-tiles
    const int b = wg >> 4;
    const int st = wg & 15;
    const int sbase = st * 64;
    const int tid = threadIdx.x;
    const int wave = tid >> 6;
    const int lane = tid & 63;
    const int l16 = lane & 15, lq = lane >> 4;
    const int vb = wave * 64;

    floatx4 acc[4][4] = {};             // [s-sub][v-sub]
    size_t arow[4];
    #pragma unroll
    for (int ss = 0; ss < 4; ++ss)
        arow[ss] = ((size_t)b * 1025 + sbase + ss * 16 + l16 + 1) * 1024;

    for (int ks = 0; ks < 32; ++ks) {
        const int k = ks * 32 + lq * 8;
        bhalf8 bb[4];
        #pragma unroll
        for (int vt = 0; vt < 4; ++vt)
            bb[vt] = ld8(&Who[(size_t)(vb + vt * 16 + l16) * H_ + k]);
        #pragma unroll
        for (int ss = 0; ss < 4; ++ss) {
            bhalf8 aa = ld8(&h_all[arow[ss] + k]);
            #pragma unroll
            for (int vt = 0; vt < 4; ++vt)
                acc[ss][vt] = __builtin_amdgcn_mfma_f32_16x16x32_bf16(aa, bb[vt], acc[ss][vt], 0, 0, 0);
        }
    }
    #pragma unroll
    for (int ss = 0; ss < 4; ++ss) {
        #pragma unroll
        for (int vt = 0; vt < 4; ++vt) {
            int v = vb + vt * 16 + l16;
            float bias = b_ho[v];
            #pragma unroll
            for (int j = 0; j < 4; ++j) {
                int s = sbase + ss * 16 + lq * 4 + j;
                out[((size_t)b << 18) + (size_t)s * V_ + v] = acc[ss][vt][j] + bias;
            }
        }
    }
}

// ---------------------------------------------------------------------------
// 5. h_final
// ---------------------------------------------------------------------------
__global__ __launch_bounds__(256) void hfinal(const u16* __restrict__ h_all,
                                              float* __restrict__ out)
{
    int i = blockIdx.x * 256 + threadIdx.x;   // 131072
    int b = i >> 10, k = i & 1023;
    out[33554432 + i] = bf2f(h_all[((size_t)b * 1025 + 1024) * 1024 + k]);
}

// ---------------------------------------------------------------------------
extern "C" void kernel_launch(void* const* d_in, const int* in_sizes, int n_in,
                              void* d_out, int out_size, void* d_ws, size_t ws_size,
                              hipStream_t stream) {
    const int*   seq    = (const int*)  d_in[0];
    const float* hidden = (const float*)d_in[1];
    const float* emb    = (const float*)d_in[2];
    const float* W_ih   = (const float*)d_in[3];
    const float* b_ih   = (const float*)d_in[4];
    const float* W_hh   = (const float*)d_in[5];
    const float* b_hh   = (const float*)d_in[6];
    const float* W_ho   = (const float*)d_in[7];
    const float* b_ho   = (const float*)d_in[8];
    float* out = (float*)d_out;

    char* ws = (char*)d_ws;
    u16*   h_all  = (u16*)ws;
    u16*   Whh_bf = (u16*)(ws + WHH_OFF);
    u16*   Who_bf = (u16*)(ws + WHO_OFF);
    float* proj   = (float*)(ws + PROJ_OFF);
    int*   cnt    = (int*)(ws + CNT_OFF);

    prep_kernel<<<5648, 256, 0, stream>>>(W_hh, W_ho, hidden, Whh_bf, Who_bf, h_all, cnt);
    proj_kernel<<<256, 256, 0, stream>>>(emb, W_ih, b_ih, b_hh, proj);
    rnn_seq<<<256, 256, 0, stream>>>(seq, proj, Whh_bf, h_all, cnt);
    out_gemm<<<2048, 256, 0, stream>>>(h_all, Who_bf, b_ho, out);
    hfinal<<<512, 256, 0, stream>>>(h_all, out);
}

// Round 12
// 2471.081 us; speedup vs baseline: 2.3168x; 1.4143x over previous
//
#include <hip/hip_runtime.h>

// ---------------------------------------------------------------------------
// VanillaRNN on MI355X (gfx950)   [R12: tile-contiguous h2 layout ->
//                                  full-line h writes, no write-allocate
//                                  HBM fetch in the per-step drain]
// B=128, S=1024, H=1024, E=512, V=256
//
//  h2 layout: [t 0..1024][g 0..7][ws 0..31][row 0..15][col 0..31] bf16
//             tile = 1KB contiguous; step = 256KB; total 262.4MB.
//  1. prep:   bf16-convert W_hh, W_ho; h2[0] = hidden; zero flags
//  2. proj:   proj[v][h] (fp32), as before
//  3. rnn_seq: R11 structure + sc0/nt flags (proven). Changes:
//             - A-frag loads from h2 tiles: 1KB fully-coalesced per wave instr
//             - reduce thread remap (row=tid>>4, cp=tid&15): each wave's
//               h-store instruction = contiguous 256B -> every 128B line
//               written whole by ONE instruction -> L2 write-allocate needs
//               no HBM fetch -> vmcnt drain ~200cy not ~900cy.
//  4. out_gemm: consumes h2: A = h2 tile (16 b-rows x 32 k), B = W_ho slice
//             in 128 VGPRs/wave; WG = (g, vblock64, tchunk128); nt out stores.
//  5. hfinal: d_out tail from h2[1024].
// ---------------------------------------------------------------------------

typedef __attribute__((ext_vector_type(8))) short bhalf8;   // 8 bf16 (4 VGPR)
typedef __attribute__((ext_vector_type(4))) float floatx4;  // 4 f32

typedef unsigned short u16;
typedef unsigned int u32;

#define B_  128
#define S_  1024
#define H_  1024
#define E_  512
#define V_  256

// h2 addressing (u16 units): idx(t,g,ws) = t*131072 + g*16384 + ws*512
#define T_STRIDE   131072        // 256KB / 2
#define G_STRIDE   16384         // 32KB / 2
#define WS_STRIDE  512           // 1KB / 2

// ws layout (bytes)
#define WHH_OFF       (268697600ull)            // h2: 1025*262144
#define WHO_OFF       (WHH_OFF + 2097152ull)
#define PROJ_OFF      (WHO_OFF + 524288ull)
#define CNT_OFF       (PROJ_OFF + 1048576ull)

#define FLAG_STRIDE   16                        // ints (64 B)
#define NFLAGS        4096
#define SPIN_CAP      16384                     // bounded spin: fail-loud

__device__ inline u16 f2bf(float f) {
    u32 u = __builtin_bit_cast(u32, f);
    u32 lsb = (u >> 16) & 1u;
    u += 0x7fffu + lsb;
    return (u16)(u >> 16);
}
__device__ inline float bf2f(u16 h) {
    u32 u = ((u32)h) << 16;
    return __builtin_bit_cast(float, u);
}
__device__ inline bhalf8 ld8(const u16* p) {
    return *(const bhalf8*)p;
}

// Flag transport at the XCD's shared L2 (R11-proven):
__device__ inline int poll_flag_l2(const int* p) {
    int v;
    asm volatile("global_load_dword %0, %1, off sc0 nt\n\ts_waitcnt vmcnt(0)"
                 : "=v"(v) : "v"(p) : "memory");
    return v;
}
__device__ inline void publish_flag_l2(int* p, int v) {
    asm volatile("global_store_dword %0, %1, off sc0"
                 :: "v"(p), "v"(v) : "memory");
}

// ---------------------------------------------------------------------------
// 1. prep
// ---------------------------------------------------------------------------
__global__ __launch_bounds__(256) void prep_kernel(
    const float* __restrict__ W_hh, const float* __restrict__ W_ho,
    const float* __restrict__ hidden,
    u16* __restrict__ Whh_bf, u16* __restrict__ Who_bf,
    u16* __restrict__ h2, int* __restrict__ cnt)
{
    int i = blockIdx.x * 256 + threadIdx.x;
    if (i < 1048576) {
        Whh_bf[i] = f2bf(W_hh[i]);
    } else if (i < 1048576 + 262144) {
        int j = i - 1048576;
        Who_bf[j] = f2bf(W_ho[j]);
    } else if (i < 1048576 + 262144 + 131072) {
        int j = i - (1048576 + 262144);
        int b = j >> 10, k = j & 1023;
        int g = b >> 4, r = b & 15, ws = k >> 5, c = k & 31;
        h2[g * G_STRIDE + ws * WS_STRIDE + r * 32 + c] = f2bf(hidden[j]);
    } else if (i < 1048576 + 262144 + 131072 + NFLAGS) {
        cnt[i - (1048576 + 262144 + 131072)] = 0;
    }
}

// ---------------------------------------------------------------------------
// 2. proj table: proj[v][h] = b_ih[h] + b_hh[h] + sum_e emb[v][e]*W_ih[h][e]
// ---------------------------------------------------------------------------
__global__ __launch_bounds__(256) void proj_kernel(
    const float* __restrict__ emb, const float* __restrict__ W_ih,
    const float* __restrict__ b_ih, const float* __restrict__ b_hh,
    float* __restrict__ proj)
{
    __shared__ float er[E_];
    int v = blockIdx.x, tid = threadIdx.x;
    er[tid]       = emb[v * E_ + tid];
    er[tid + 256] = emb[v * E_ + 256 + tid];
    __syncthreads();
    const float4* x = (const float4*)er;
    #pragma unroll
    for (int j = 0; j < 4; ++j) {
        int hc = tid + j * 256;
        const float4* w = (const float4*)&W_ih[(size_t)hc * E_];
        float s = 0.f;
        #pragma unroll 8
        for (int e = 0; e < E_ / 4; ++e) {
            float4 ww = w[e]; float4 xx = x[e];
            s += ww.x * xx.x + ww.y * xx.y + ww.z * xx.z + ww.w * xx.w;
        }
        proj[v * H_ + hc] = s + b_ih[hc] + b_hh[hc];
    }
}

// ---------------------------------------------------------------------------
// 3. persistent sequential RNN kernel  (R11 sync, h2 tile layout)
//    grid = 256 WGs x 256 threads. group g = wg&7 (XCD), 32 WGs/group,
//    WG owns 32 h-cols; 4 waves split K=1024; LDS reduce; tanh; tile store.
// ---------------------------------------------------------------------------
__global__ __launch_bounds__(256) void rnn_seq(
    const int* __restrict__ seq, const float* __restrict__ proj,
    const u16* __restrict__ Whh, u16* __restrict__ h2,
    int* __restrict__ cnt)
{
    const int wg = blockIdx.x;
    const int g = wg & 7;
    const int wslot = wg >> 3;          // 0..31 within group
    const int colbase = wslot * 32;
    const int tid = threadIdx.x;
    const int wave = tid >> 6;
    const int lane = tid & 63;
    const int l16 = lane & 15, lq = lane >> 4;
    const int kb = wave * 256;          // wave's K-slice base

    // W_hh slice resident in registers: 2 col-tiles x 8 k-steps
    bhalf8 bfrag[2][8];
    #pragma unroll
    for (int tt = 0; tt < 2; ++tt) {
        #pragma unroll
        for (int ks = 0; ks < 8; ++ks) {
            bfrag[tt][ks] = ld8(&Whh[(size_t)(colbase + tt * 16 + l16) * H_
                                     + kb + ks * 32 + lq * 8]);
        }
    }

    __shared__ float red[4][2][16][17];   // [wave][tile][row][col+pad]

    int* gflags = cnt + g * 32 * FLAG_STRIDE;
    int* myflag = gflags + wslot * FLAG_STRIDE;
    // wave w consumes h cols [w*256, w*256+256) = wslots [w*8, w*8+8)
    int* pollp  = gflags + (wave * 8 + (lane & 7)) * FLAG_STRIDE;

    // A-frag source: tile (t, g, wave*8+ks), lane offset l16*32 + lq*8
    const int aLane = g * G_STRIDE + wave * 8 * WS_STRIDE + l16 * 32 + lq * 8;

    // reduce-phase fixed indices (remapped for coalesced tile stores):
    const int row = tid >> 4;           // batch row within group (0..15)
    const int cp  = tid & 15;           // col pair (cols 2cp, 2cp+1)
    const int c0 = 2 * cp, c1 = c0 + 1;
    // store addr within tile: row*32 + cp*2  (u16), tile = (t+1, g, wslot)
    const int sLane = g * G_STRIDE + wslot * WS_STRIDE + row * 32 + cp * 2;
    const int seqBase = (g * 16 + row) * S_;

    for (int t = 0; t < S_; ++t) {
        // early load (independent of h): token
        int tok = seq[seqBase + t];

        // --- MFMA: z_partial[16 x 32] over this wave's K-slice ---
        const u16* hp = h2 + (size_t)t * T_STRIDE + aLane;
        floatx4 acc0 = {0.f, 0.f, 0.f, 0.f};
        floatx4 acc1 = {0.f, 0.f, 0.f, 0.f};
        #pragma unroll
        for (int ks = 0; ks < 8; ++ks) {
            bhalf8 a = ld8(hp + ks * WS_STRIDE);
            acc0 = __builtin_amdgcn_mfma_f32_16x16x32_bf16(a, bfrag[0][ks], acc0, 0, 0, 0);
            acc1 = __builtin_amdgcn_mfma_f32_16x16x32_bf16(a, bfrag[1][ks], acc1, 0, 0, 0);
        }
        float2 pj = *(const float2*)&proj[tok * H_ + colbase + c0];

        #pragma unroll
        for (int j = 0; j < 4; ++j) {    // D layout: row=(lq*4+j), col=l16
            red[wave][0][lq * 4 + j][l16] = acc0[j];
            red[wave][1][lq * 4 + j][l16] = acc1[j];
        }
        __syncthreads();

        // --- reduce 4 waves + x_proj + tanh + bf16 tile store ---
        float z0 = red[0][c0 >> 4][row][c0 & 15] + red[1][c0 >> 4][row][c0 & 15]
                 + red[2][c0 >> 4][row][c0 & 15] + red[3][c0 >> 4][row][c0 & 15] + pj.x;
        float z1 = red[0][c1 >> 4][row][c1 & 15] + red[1][c1 >> 4][row][c1 & 15]
                 + red[2][c1 >> 4][row][c1 & 15] + red[3][c1 >> 4][row][c1 & 15] + pj.y;
        u32 pack = (u32)f2bf(tanhf(z0)) | ((u32)f2bf(tanhf(z1)) << 16);
        // wave w stores contiguous 256B of the 1KB tile -> full-line writes
        *(u32*)&h2[(size_t)(t + 1) * T_STRIDE + sLane] = pack;

        // --- sync: drains all waves' h stores to the XCD L2 (vmcnt 0 before
        //     barrier; no HBM allocate-fetch now) + protects `red` ---
        __syncthreads();

        // --- publish: sc0 write-through store -> this XCD's L2 ---
        if (tid == 0)
            publish_flag_l2(myflag, t + 1);

        // --- per-wave wait on its 8 producer WGs via sc0+nt L2 reads ---
        if (t < S_ - 1) {
            const int target = t + 1;
            int spins = 0;
            for (;;) {
                int v = (lane < 8) ? poll_flag_l2(pollp) : 0x7fffffff;
                if (__all(v >= target)) break;
                if (++spins > SPIN_CAP) break;   // safety valve
            }
            asm volatile("" ::: "memory");   // no h-load hoist above the wait
        }
    }
}

// ---------------------------------------------------------------------------
// 4. output GEMM from h2: out[b][s][v] = dot(h2[s+1; b,:], W_ho[v,:]) + b_ho[v]
//    WG = (g, vblock, tchunk): 8 x 4 x 8 = 256 WGs x 256 thr.
//    Wave w: vtile = vblock*64 + w*16 (W_ho slice in 128 VGPRs, full K);
//    per t: A = h2 tiles (16 b-rows x 32 k), 32 MFMAs (2 chains).
// ---------------------------------------------------------------------------
__global__ __launch_bounds__(256) void out_gemm(
    const u16* __restrict__ h2, const u16* __restrict__ Who,
    const float* __restrict__ b_ho, float* __restrict__ out)
{
    const int wg = blockIdx.x;          // 256
    const int g  = wg & 7;
    const int vb = (wg >> 3) & 3;
    const int tc = wg >> 5;             // 0..7
    const int tid = threadIdx.x;
    const int wave = tid >> 6;
    const int lane = tid & 63;
    const int l16 = lane & 15, lq = lane >> 4;
    const int v = vb * 64 + wave * 16 + l16;   // this lane's vocab column

    // W_ho slice, full K: 32 k-steps
    bhalf8 bw[32];
    #pragma unroll
    for (int ks = 0; ks < 32; ++ks)
        bw[ks] = ld8(&Who[(size_t)v * H_ + ks * 32 + lq * 8]);
    const float bias = b_ho[v];

    const int aLane = g * G_STRIDE + l16 * 32 + lq * 8;
    // store rows: b = g*16 + lq*4 + j
    size_t oRow[4];
    #pragma unroll
    for (int j = 0; j < 4; ++j)
        oRow[4 - 1 - j] = 0;            // placate compiler; overwritten below
    #pragma unroll
    for (int j = 0; j < 4; ++j)
        oRow[j] = ((size_t)(g * 16 + lq * 4 + j) << 18) + v;

    for (int t = tc * 128; t < tc * 128 + 128; ++t) {
        const u16* hp = h2 + (size_t)(t + 1) * T_STRIDE + aLane;
        floatx4 accE = {0.f, 0.f, 0.f, 0.f};
        floatx4 accO = {0.f, 0.f, 0.f, 0.f};
        #pragma unroll
        for (int ks = 0; ks < 32; ks += 2) {
            bhalf8 a0 = ld8(hp + ks * WS_STRIDE);
            bhalf8 a1 = ld8(hp + ks * WS_STRIDE + WS_STRIDE);
            accE = __builtin_amdgcn_mfma_f32_16x16x32_bf16(a0, bw[ks],     accE, 0, 0, 0);
            accO = __builtin_amdgcn_mfma_f32_16x16x32_bf16(a1, bw[ks + 1], accO, 0, 0, 0);
        }
        #pragma unroll
        for (int j = 0; j < 4; ++j) {
            float z = accE[j] + accO[j] + bias;
            __builtin_nontemporal_store(z, &out[oRow[j] + (size_t)t * V_]);
        }
    }
}

// ---------------------------------------------------------------------------
// 5. h_final: d_out tail = fp32(h2[1024])
// ---------------------------------------------------------------------------
__global__ __launch_bounds__(256) void hfinal(const u16* __restrict__ h2,
                                              float* __restrict__ out)
{
    int i = blockIdx.x * 256 + threadIdx.x;   // 131072
    int b = i >> 10, k = i & 1023;
    int g = b >> 4, r = b & 15, ws = k >> 5, c = k & 31;
    out[33554432 + i] =
        bf2f(h2[(size_t)1024 * T_STRIDE + g * G_STRIDE + ws * WS_STRIDE + r * 32 + c]);
}

// ---------------------------------------------------------------------------
extern "C" void kernel_launch(void* const* d_in, const int* in_sizes, int n_in,
                              void* d_out, int out_size, void* d_ws, size_t ws_size,
                              hipStream_t stream) {
    const int*   seq    = (const int*)  d_in[0];
    const float* hidden = (const float*)d_in[1];
    const float* emb    = (const float*)d_in[2];
    const float* W_ih   = (const float*)d_in[3];
    const float* b_ih   = (const float*)d_in[4];
    const float* W_hh   = (const float*)d_in[5];
    const float* b_hh   = (const float*)d_in[6];
    const float* W_ho   = (const float*)d_in[7];
    const float* b_ho   = (const float*)d_in[8];
    float* out = (float*)d_out;

    char* ws = (char*)d_ws;
    u16*   h2     = (u16*)ws;
    u16*   Whh_bf = (u16*)(ws + WHH_OFF);
    u16*   Who_bf = (u16*)(ws + WHO_OFF);
    float* proj   = (float*)(ws + PROJ_OFF);
    int*   cnt    = (int*)(ws + CNT_OFF);

    prep_kernel<<<5648, 256, 0, stream>>>(W_hh, W_ho, hidden, Whh_bf, Who_bf, h2, cnt);
    proj_kernel<<<256, 256, 0, stream>>>(emb, W_ih, b_ih, b_hh, proj);
    rnn_seq<<<256, 256, 0, stream>>>(seq, proj, Whh_bf, h2, cnt);
    out_gemm<<<256, 256, 0, stream>>>(h2, Who_bf, b_ho, out);
    hfinal<<<512, 256, 0, stream>>>(h2, out);
}